// Round 5
// baseline (131.555 us; speedup 1.0000x reference)
//
#include <hip/hip_runtime.h>

// HumanComposer3D: per-pixel composite over K=8 layers.
// Persistent-block, cross-tile software pipeline: next tile's global loads
// stay in flight across compute (raw s_barrier + lgkmcnt-only waits; no
// __syncthreads -> no vmcnt(0) drain).
//
// texels: (B,H,W,8,5) f32  [r,g,b,a,label]
// zbuf:   (B,H,W,8)   f32
// bkg:    (3,)        f32
// out (concat, f32): image (npix*4) | depth (npix) | label (npix) | human (npix*8*4)

#define TW  40   // texel LDS words per pixel (10 float4 slots, XOR-swizzled)
#define HWD 36   // human LDS words per pixel (8 float4 slots + 4 pad)

typedef float vf4 __attribute__((ext_vector_type(4)));

__device__ __forceinline__ int slotOf(int f4, int p) {
    return (f4 < 8) ? (f4 ^ (p & 7)) : (8 + ((f4 - 8) ^ (p & 1)));
}

// Barrier that completes this thread's LDS ops but leaves global (vmcnt)
// prefetch loads in flight. sched_barrier(0) pins post-barrier LDS ops.
__device__ __forceinline__ void sync_lgkm() {
    asm volatile("s_waitcnt lgkmcnt(0)" ::: "memory");
    __builtin_amdgcn_s_barrier();
    __builtin_amdgcn_sched_barrier(0);
}

__global__ __launch_bounds__(256) void composer_kernel(
    const float* __restrict__ texels,
    const float* __restrict__ zbuf,
    const float* __restrict__ bkg,
    float* __restrict__ out,
    int npix)
{
    __shared__ float lds[256 * TW];   // 40960 B; reused for human staging (256*36 words)

    const int tid   = threadIdx.x;
    const int nfull = npix >> 8;      // number of full 256-pixel tiles
    const float bk0 = bkg[0], bk1 = bkg[1], bk2 = bkg[2];
    const size_t np = (size_t)npix;

    int tile = blockIdx.x;
    if (tile < nfull) {
        float4 pf[10];
        float4 pz0, pz1;
        // ---- initial prefetch (tile 0 of this block) ----
        {
            const float4* gt = reinterpret_cast<const float4*>(texels) + (size_t)tile * 2560;
            #pragma unroll
            for (int i = 0; i < 10; ++i) pf[i] = gt[i * 256 + tid];
            const float4* zp = reinterpret_cast<const float4*>(zbuf) + (((size_t)tile << 8) + tid) * 2;
            pz0 = zp[0]; pz1 = zp[1];
        }

        while (true) {
            const int base     = tile << 8;
            const int pix      = base + tid;
            const int nexttile = tile + (int)gridDim.x;
            const bool havenext = (nexttile < nfull);

            // B1: previous tile's cooperative human store has consumed LDS
            sync_lgkm();

            // ---- stage texels (prefetch regs) -> LDS, swizzled ----
            #pragma unroll
            for (int i = 0; i < 10; ++i) {
                int idx = i * 256 + tid;
                int p = idx / 10, f4 = idx - 10 * p;
                *reinterpret_cast<float4*>(&lds[p * TW + slotOf(f4, p) * 4]) = pf[i];
            }

            // capture this tile's zbuf before pz regs are overwritten
            float z[8] = { pz0.x, pz0.y, pz0.z, pz0.w, pz1.x, pz1.y, pz1.z, pz1.w };

            // ---- issue NEXT tile's prefetch; stays in flight across compute ----
            if (havenext) {
                const float4* gt = reinterpret_cast<const float4*>(texels) + (size_t)nexttile * 2560;
                #pragma unroll
                for (int i = 0; i < 10; ++i) pf[i] = gt[i * 256 + tid];
                const float4* zp = reinterpret_cast<const float4*>(zbuf) + (((size_t)nexttile << 8) + tid) * 2;
                pz0 = zp[0]; pz1 = zp[1];
            }

            // B2: texel LDS visible to all threads
            sync_lgkm();

            // ---- LDS -> registers (swizzled, b128) ----
            float t[40];
            #pragma unroll
            for (int f4 = 0; f4 < 10; ++f4) {
                float4 v = *reinterpret_cast<const float4*>(&lds[tid * TW + slotOf(f4, tid) * 4]);
                t[4*f4+0]=v.x; t[4*f4+1]=v.y; t[4*f4+2]=v.z; t[4*f4+3]=v.w;
            }

            // ---- compositing scan, k = 7..0 ----
            float r = bk0, g = bk1, b = bk2;
            float a = 0.0f, d = 100.0f, l = 8.0f;
            #pragma unroll
            for (int k = 7; k >= 0; --k) {
                const float lr = t[5*k+0], lg = t[5*k+1], lb = t[5*k+2];
                const float la = t[5*k+3], ll = t[5*k+4];
                const float zd = z[k];
                const float om = 1.0f - la;
                r = fmaf(lr, la, r * om);
                g = fmaf(lg, la, g * om);
                b = fmaf(lb, la, b * om);
                a = fmaxf(la, a);
                if (zd > 0.0f)  d = fmaf(zd, la, d * om);
                if (zd >= 0.0f) l = (la > 0.5f) ? ll : l;
            }

            {
                vf4 img = { r, g, b, a };
                __builtin_nontemporal_store(img, reinterpret_cast<vf4*>(out) + pix);
                __builtin_nontemporal_store(d, out + np*4 + pix);
                const float lo = (l > 7.5f) ? -1.0f : (float)__float2int_rn(l);
                __builtin_nontemporal_store(lo, out + np*5 + pix);
            }

            // ---- per-layer integer labels + human colors (register-only) ----
            int li[8];
            #pragma unroll
            for (int k = 0; k < 8; ++k)
                li[k] = (z[k] >= 0.0f) ? __float2int_rn(t[5*k+4]) : -1;

            float4 hv[8];
            #pragma unroll
            for (int n = 0; n < 8; ++n) {
                float cr=0.f, cg=0.f, cb=0.f, ca=0.f; bool found=false;
                #pragma unroll
                for (int k = 0; k < 8; ++k) {
                    bool m = (!found) && (li[k] == n);
                    if (m) { cr=t[5*k+0]; cg=t[5*k+1]; cb=t[5*k+2]; ca=t[5*k+3]; found=true; }
                }
                const float oma = 1.0f - ca;
                hv[n] = make_float4(fmaf(cr, ca, bk0 * oma),
                                    fmaf(cg, ca, bk1 * oma),
                                    fmaf(cb, ca, bk2 * oma),
                                    ca);
            }

            // B3: every thread's texel-LDS read data has landed (lgkmcnt(0) above)
            sync_lgkm();

            // ---- stage human images to LDS ----
            {
                float* hb = &lds[tid * HWD];
                #pragma unroll
                for (int n = 0; n < 8; ++n)
                    *reinterpret_cast<float4*>(&hb[n*4]) = hv[n];
            }

            // B4: human LDS visible
            sync_lgkm();

            // ---- cooperative coalesced LDS -> global human store ----
            {
                vf4* gh = reinterpret_cast<vf4*>(out + np*6) + (size_t)base * 8;
                #pragma unroll
                for (int i = 0; i < 8; ++i) {
                    int idx = i * 256 + tid;
                    int P = idx >> 3, c = idx & 7;
                    float4 s = *reinterpret_cast<const float4*>(&lds[P * HWD + c * 4]);
                    vf4 h = { s.x, s.y, s.z, s.w };
                    __builtin_nontemporal_store(h, gh + idx);
                }
            }

            if (!havenext) break;
            tile = nexttile;
        }
    }

    // ---- partial tail tile (npix % 256 != 0): direct per-pixel path ----
    const int rem = npix & 255;
    if (rem && (int)blockIdx.x == (nfull % (int)gridDim.x)) {
        const int pix = (nfull << 8) + tid;
        if (pix < npix) {
            float t[40]; float z[8];
            const float4* tp = reinterpret_cast<const float4*>(texels + (size_t)pix * 40);
            #pragma unroll
            for (int i = 0; i < 10; ++i) {
                float4 v = tp[i];
                t[4*i+0]=v.x; t[4*i+1]=v.y; t[4*i+2]=v.z; t[4*i+3]=v.w;
            }
            const float4* zp = reinterpret_cast<const float4*>(zbuf + (size_t)pix * 8);
            float4 v0 = zp[0], v1 = zp[1];
            z[0]=v0.x; z[1]=v0.y; z[2]=v0.z; z[3]=v0.w;
            z[4]=v1.x; z[5]=v1.y; z[6]=v1.z; z[7]=v1.w;

            float r = bk0, g = bk1, b = bk2;
            float a = 0.0f, d = 100.0f, l = 8.0f;
            #pragma unroll
            for (int k = 7; k >= 0; --k) {
                const float lr = t[5*k+0], lg = t[5*k+1], lb = t[5*k+2];
                const float la = t[5*k+3], ll = t[5*k+4];
                const float zd = z[k];
                const float om = 1.0f - la;
                r = fmaf(lr, la, r * om);
                g = fmaf(lg, la, g * om);
                b = fmaf(lb, la, b * om);
                a = fmaxf(la, a);
                if (zd > 0.0f)  d = fmaf(zd, la, d * om);
                if (zd >= 0.0f) l = (la > 0.5f) ? ll : l;
            }
            vf4 img = { r, g, b, a };
            __builtin_nontemporal_store(img, reinterpret_cast<vf4*>(out) + pix);
            __builtin_nontemporal_store(d, out + np*4 + pix);
            const float lo = (l > 7.5f) ? -1.0f : (float)__float2int_rn(l);
            __builtin_nontemporal_store(lo, out + np*5 + pix);

            int li[8];
            #pragma unroll
            for (int k = 0; k < 8; ++k)
                li[k] = (z[k] >= 0.0f) ? __float2int_rn(t[5*k+4]) : -1;

            vf4* o_h = reinterpret_cast<vf4*>(out + np*6) + (size_t)pix * 8;
            #pragma unroll
            for (int n = 0; n < 8; ++n) {
                float cr=0.f, cg=0.f, cb=0.f, ca=0.f; bool found=false;
                #pragma unroll
                for (int k = 0; k < 8; ++k) {
                    bool m = (!found) && (li[k] == n);
                    if (m) { cr=t[5*k+0]; cg=t[5*k+1]; cb=t[5*k+2]; ca=t[5*k+3]; found=true; }
                }
                const float oma = 1.0f - ca;
                vf4 h = { fmaf(cr,ca,bk0*oma), fmaf(cg,ca,bk1*oma),
                          fmaf(cb,ca,bk2*oma), ca };
                __builtin_nontemporal_store(h, o_h + n);
            }
        }
    }
}

extern "C" void kernel_launch(void* const* d_in, const int* in_sizes, int n_in,
                              void* d_out, int out_size, void* d_ws, size_t ws_size,
                              hipStream_t stream) {
    const float* texels = (const float*)d_in[0];
    const float* zbuf   = (const float*)d_in[1];
    const float* bkg    = (const float*)d_in[2];
    float* out = (float*)d_out;

    const int npix   = in_sizes[1] / 8;          // B*H*W from zbuf element count
    const int ntiles = (npix + 255) / 256;
    int blocks = ntiles < 1024 ? ntiles : 1024;  // persistent: 4 blocks/CU resident
    if (blocks < 1) blocks = 1;
    hipLaunchKernelGGL(composer_kernel, dim3(blocks), dim3(256), 0, stream,
                       texels, zbuf, bkg, out, npix);
}

// Round 6
// 68.471 us; speedup vs baseline: 1.9213x; 1.9213x over previous
//
#include <hip/hip_runtime.h>

// HumanComposer3D: per-pixel composite over K=8 layers, LDS-staged for coalescing.
// texels: (B,H,W,8,5) f32  [r,g,b,a,label]
// zbuf:   (B,H,W,8)   f32
// bkg:    (3,)        f32
// out (concat, f32): image (npix*4) | depth (npix) | label (npix) | human (npix*8*4)
//
// Round-3 configuration (best measured: 68.6 us, 94% of delivered-byte copy
// ceiling). Dense non-persistent grid keeps the resident working set compact
// -> L3 serves ~116 MB of reads; LDS staging makes all global ops coalesced.

#define TPAD 41   // texel LDS pixel stride in words; 41%32=9, gcd(9,32)=1 -> conflict-free reads
#define HPAD 33   // human LDS pixel stride in words; conflict-free writes

typedef float vf4 __attribute__((ext_vector_type(4)));   // nontemporal-store-compatible

__global__ __launch_bounds__(256) void composer_kernel(
    const float* __restrict__ texels,
    const float* __restrict__ zbuf,
    const float* __restrict__ bkg,
    float* __restrict__ out,
    int npix)
{
    __shared__ float lds[256 * TPAD];   // 41,984 B; reused for human staging (256*33 words)

    const int tid  = threadIdx.x;
    const int base = blockIdx.x * 256;          // first pixel of this block
    const bool full = (base + 256 <= npix);
    const float bk0 = bkg[0], bk1 = bkg[1], bk2 = bkg[2];
    const size_t np = (size_t)npix;

    float t[40];
    float z[8];
    int   pix = base + tid;

    if (full) {
        // ---- phase 1: cooperative coalesced global->LDS texel load ----
        const float4* gt = reinterpret_cast<const float4*>(texels) + (size_t)base * 10;
        #pragma unroll
        for (int i = 0; i < 10; ++i) {
            int idx = i * 256 + tid;        // float4 index within block
            float4 v = gt[idx];
            int p  = idx / 10;              // pixel within block
            int f4 = idx % 10;
            float* d = &lds[p * TPAD + f4 * 4];
            d[0] = v.x; d[1] = v.y; d[2] = v.z; d[3] = v.w;
        }
        __syncthreads();

        // ---- phase 2: LDS -> registers (conflict-free, stride 41) ----
        {
            const float* s = &lds[tid * TPAD];
            #pragma unroll
            for (int e = 0; e < 40; ++e) t[e] = s[e];
        }
        {
            const float4* zp = reinterpret_cast<const float4*>(zbuf + (size_t)pix * 8);
            float4 v0 = zp[0], v1 = zp[1];
            z[0]=v0.x; z[1]=v0.y; z[2]=v0.z; z[3]=v0.w;
            z[4]=v1.x; z[5]=v1.y; z[6]=v1.z; z[7]=v1.w;
        }
        __syncthreads();   // all LDS reads done before human staging overwrites
    } else {
        // tail block (not hit for 768x768x2, but keep correct): direct loads
        if (pix < npix) {
            const float4* tp = reinterpret_cast<const float4*>(texels + (size_t)pix * 40);
            #pragma unroll
            for (int i = 0; i < 10; ++i) {
                float4 v = tp[i];
                t[4*i+0]=v.x; t[4*i+1]=v.y; t[4*i+2]=v.z; t[4*i+3]=v.w;
            }
            const float4* zp = reinterpret_cast<const float4*>(zbuf + (size_t)pix * 8);
            float4 v0 = zp[0], v1 = zp[1];
            z[0]=v0.x; z[1]=v0.y; z[2]=v0.z; z[3]=v0.w;
            z[4]=v1.x; z[5]=v1.y; z[6]=v1.z; z[7]=v1.w;
        }
    }

    const bool active = full || (pix < npix);
    if (active) {
        // ---- compositing scan, k = 7..0 ----
        float r = bk0, g = bk1, b = bk2;
        float a = 0.0f, d = 100.0f, l = 8.0f;
        #pragma unroll
        for (int k = 7; k >= 0; --k) {
            const float lr = t[5*k+0], lg = t[5*k+1], lb = t[5*k+2];
            const float la = t[5*k+3], ll = t[5*k+4];
            const float zd = z[k];
            const float om = 1.0f - la;
            r = fmaf(lr, la, r * om);
            g = fmaf(lg, la, g * om);
            b = fmaf(lb, la, b * om);
            a = fmaxf(la, a);
            if (zd > 0.0f)  d = fmaf(zd, la, d * om);
            if (zd >= 0.0f) l = (la > 0.5f) ? ll : l;
        }

        // composite image / depth / label (coalesced, nontemporal)
        {
            vf4 img = { r, g, b, a };
            __builtin_nontemporal_store(img, reinterpret_cast<vf4*>(out) + pix);
            __builtin_nontemporal_store(d, out + np*4 + pix);
            const float lo = (l > 7.5f) ? -1.0f : (float)__float2int_rn(l);
            __builtin_nontemporal_store(lo, out + np*5 + pix);
        }

        // ---- per-layer integer labels ----
        int li[8];
        #pragma unroll
        for (int k = 0; k < 8; ++k)
            li[k] = (z[k] >= 0.0f) ? __float2int_rn(t[5*k+4]) : -1;

        // ---- human images ----
        if (full) {
            // stage to LDS (stride 33: conflict-free writes)
            float* hb = &lds[tid * HPAD];
            #pragma unroll
            for (int n = 0; n < 8; ++n) {
                float cr=0.f, cg=0.f, cb=0.f, ca=0.f; bool found=false;
                #pragma unroll
                for (int k = 0; k < 8; ++k) {
                    bool m = (!found) && (li[k] == n);
                    if (m) { cr=t[5*k+0]; cg=t[5*k+1]; cb=t[5*k+2]; ca=t[5*k+3]; found=true; }
                }
                const float oma = 1.0f - ca;
                hb[n*4+0] = fmaf(cr, ca, bk0 * oma);
                hb[n*4+1] = fmaf(cg, ca, bk1 * oma);
                hb[n*4+2] = fmaf(cb, ca, bk2 * oma);
                hb[n*4+3] = ca;
            }
        } else {
            vf4* o_h = reinterpret_cast<vf4*>(out + np*6) + (size_t)pix * 8;
            #pragma unroll
            for (int n = 0; n < 8; ++n) {
                float cr=0.f, cg=0.f, cb=0.f, ca=0.f; bool found=false;
                #pragma unroll
                for (int k = 0; k < 8; ++k) {
                    bool m = (!found) && (li[k] == n);
                    if (m) { cr=t[5*k+0]; cg=t[5*k+1]; cb=t[5*k+2]; ca=t[5*k+3]; found=true; }
                }
                const float oma = 1.0f - ca;
                vf4 h = { fmaf(cr,ca,bk0*oma), fmaf(cg,ca,bk1*oma),
                          fmaf(cb,ca,bk2*oma), ca };
                __builtin_nontemporal_store(h, o_h + n);
            }
        }
    }

    if (full) {
        __syncthreads();
        // ---- phase 3b: cooperative coalesced LDS->global human store ----
        vf4* gh = reinterpret_cast<vf4*>(out + np*6) + (size_t)base * 8;
        #pragma unroll
        for (int i = 0; i < 8; ++i) {
            int idx = i * 256 + tid;        // float4 index within block region
            int P = idx >> 3;               // pixel within block
            int c = idx & 7;                // float4 within pixel
            const float* s = &lds[P * HPAD + c * 4];
            vf4 h = { s[0], s[1], s[2], s[3] };
            __builtin_nontemporal_store(h, gh + idx);
        }
    }
}

extern "C" void kernel_launch(void* const* d_in, const int* in_sizes, int n_in,
                              void* d_out, int out_size, void* d_ws, size_t ws_size,
                              hipStream_t stream) {
    const float* texels = (const float*)d_in[0];
    const float* zbuf   = (const float*)d_in[1];
    const float* bkg    = (const float*)d_in[2];
    float* out = (float*)d_out;

    const int npix = in_sizes[1] / 8;           // B*H*W from zbuf element count
    const int blocks = (npix + 255) / 256;
    hipLaunchKernelGGL(composer_kernel, dim3(blocks), dim3(256), 0, stream,
                       texels, zbuf, bkg, out, npix);
}